// Round 4
// baseline (7094.747 us; speedup 1.0000x reference)
//
#include <hip/hip_runtime.h>

typedef unsigned short u16;
#define DI __device__ __forceinline__

constexpr int N_ = 50000;
constexpr int E_ = 400000;
constexpr int G_ = 64;
constexpr int EPB = 8;          // edges per block in edge_scalar

DI float bf2f(u16 h) { union { unsigned u; float f; } c; c.u = ((unsigned)h) << 16; return c.f; }
DI u16 f2bf(float f) {
    union { unsigned u; float f; } c; c.f = f;
    unsigned u = c.u;
    u += 0x7fffu + ((u >> 16) & 1u);   // RNE
    return (u16)(u >> 16);
}

// ---------------------------------------------------------------------------
// Named kernel (stub symbol kept AND launched): zeros agg0+agg1 (40 MB) and
// runs the float-array dtype detector (bf16-packed vs f32) on x, writing a
// flag int into d_ws that all later kernels read.
//   bf16-packed: u16[2k] are bf16 of N(0,1) -> sane exponents, ~no zeros.
//   f32 (incl. bf16-upcast): u16[2k] are low mantissa halves -> zeros (upcast)
//   or wild exponents (general).
// ---------------------------------------------------------------------------
__global__ __launch_bounds__(256)
void ModelGNN_35304631174019_kernel(float4* __restrict__ aggz,
                                    const u16* __restrict__ x,
                                    int* __restrict__ flag)
{
    int i = blockIdx.x * 256 + threadIdx.x;
    if (i < 2500000) aggz[i] = make_float4(0.f, 0.f, 0.f, 0.f);
    if (i == 0) {
        int zeros = 0, sane = 0;
        for (int k = 0; k < 32; ++k) {
            u16 v = x[2 * k];
            if (v == 0) zeros++;
            int e = (v >> 7) & 255;
            if (e >= 97 && e <= 159) sane++;
        }
        *flag = (zeros >= 8 || sane <= 24) ? 1 : 0;   // 1 = f32, 0 = bf16-packed
    }
}

// ---------------------------------------------------------------------------
// edge_scalar: fused per-edge 3-layer MLP + clamped scatter-max, pure VALU.
// Block = 320 threads (thread = output channel), 8 edges per block.
// Original weight layouts: W1[k*300+t] (k<K1), W2[k*300+t], W3[k*100+t].
// first=1: in = [xi(7) | xj-xi(7)] from X.        K1=14.
// first=0: in = [hi(100) | hj-hi(100)] from fp32 H0. K1=200.
// relu(where(cnt>0,segmax,0)) == int atomicMax of relu'd msgs into 0-init buf.
// Float-array loads dispatched on *flag (block-uniform).
// ---------------------------------------------------------------------------
__global__ __launch_bounds__(320)
void edge_scalar(const int first, const int* __restrict__ flag,
                 const void* __restrict__ X, const float* __restrict__ H0,
                 const int* __restrict__ ei,
                 const void* __restrict__ W1, const void* __restrict__ B1,
                 const void* __restrict__ W2, const void* __restrict__ B2,
                 const void* __restrict__ W3, const void* __restrict__ B3,
                 float* __restrict__ agg)
{
    __shared__ float IN[EPB][208];
    __shared__ float H1[EPB][304];
    __shared__ float H2[EPB][304];

    const int t  = threadIdx.x;
    const int e0 = blockIdx.x * EPB;
    const int K1 = first ? 14 : 200;
    const int isf = *flag;

    auto body = [&](auto LD) {
        // ---- gather inputs into LDS
        for (int idx = t; idx < EPB * K1; idx += 320) {
            int e   = idx / K1, k = idx - e * K1;
            int dst = ei[E_ + e0 + e];     // x_i (target)
            int src = ei[e0 + e];          // x_j (source)
            float v;
            if (first) {
                v = (k < 7) ? LD(X, dst * 7 + k)
                            : LD(X, src * 7 + (k - 7)) - LD(X, dst * 7 + (k - 7));
            } else {
                v = (k < 100) ? H0[dst * 100 + k]
                              : H0[src * 100 + (k - 100)] - H0[dst * 100 + (k - 100)];
            }
            IN[e][k] = v;
        }
        __syncthreads();

        // ---- layer A: in[K1] -> 300, relu
        if (t < 300) {
            float acc[EPB];
            const float b = LD(B1, t);
            #pragma unroll
            for (int e = 0; e < EPB; ++e) acc[e] = b;
            for (int k = 0; k < K1; ++k) {
                float wv = LD(W1, k * 300 + t);
                #pragma unroll
                for (int e = 0; e < EPB; ++e) acc[e] = fmaf(IN[e][k], wv, acc[e]);
            }
            #pragma unroll
            for (int e = 0; e < EPB; ++e) H1[e][t] = fmaxf(acc[e], 0.f);
        }
        __syncthreads();

        // ---- layer B: 300 -> 300, relu
        if (t < 300) {
            float acc[EPB];
            const float b = LD(B2, t);
            #pragma unroll
            for (int e = 0; e < EPB; ++e) acc[e] = b;
            for (int k = 0; k < 300; ++k) {
                float wv = LD(W2, k * 300 + t);
                #pragma unroll
                for (int e = 0; e < EPB; ++e) acc[e] = fmaf(H1[e][k], wv, acc[e]);
            }
            #pragma unroll
            for (int e = 0; e < EPB; ++e) H2[e][t] = fmaxf(acc[e], 0.f);
        }
        __syncthreads();

        // ---- layer C: 300 -> 100, relu-clamp, scatter-max
        if (t < 100) {
            float acc[EPB];
            const float b = LD(B3, t);
            #pragma unroll
            for (int e = 0; e < EPB; ++e) acc[e] = b;
            for (int k = 0; k < 300; ++k) {
                float wv = LD(W3, k * 100 + t);
                #pragma unroll
                for (int e = 0; e < EPB; ++e) acc[e] = fmaf(H2[e][k], wv, acc[e]);
            }
            #pragma unroll
            for (int e = 0; e < EPB; ++e) {
                int dst = ei[E_ + e0 + e];
                float v = fmaxf(acc[e], 0.f);
                atomicMax((int*)(agg + (size_t)dst * 100 + t), __float_as_int(v));
            }
        }
    };

    if (isf) body([](const void* p, int i) -> float { return ((const float*)p)[i]; });
    else     body([](const void* p, int i) -> float { return bf2f(((const u16*)p)[i]); });
}

// ---------------------------------------------------------------------------
// pool: one block per graph (batch sorted -> binary-search bounds).
// pooled[g] = [addp(100) | meanp(100) | maxp(100) | u(2)]
// ---------------------------------------------------------------------------
__global__ __launch_bounds__(256)
void pool(const float* __restrict__ agg1, const int* __restrict__ batch,
          const void* __restrict__ u, const int* __restrict__ flag,
          float* __restrict__ pooled)
{
    const int g = blockIdx.x;
    int lo = 0, hi = N_;
    while (lo < hi) { int mid = (lo + hi) >> 1; if (batch[mid] < g) lo = mid + 1; else hi = mid; }
    const int start = lo;
    int lo2 = start, hi2 = N_;
    while (lo2 < hi2) { int mid = (lo2 + hi2) >> 1; if (batch[mid] < g + 1) lo2 = mid + 1; else hi2 = mid; }
    const int end = lo2;

    const int c = threadIdx.x & 127, half = threadIdx.x >> 7;
    float sm = 0.f, mx = 0.f;
    if (c < 100)
        for (int n = start + half; n < end; n += 2) {
            float v = agg1[(size_t)n * 100 + c];
            sm += v; mx = fmaxf(mx, v);
        }
    __shared__ float ssum[128], smax[128];
    if (half) { ssum[c] = sm; smax[c] = mx; }
    __syncthreads();
    if (!half && c < 100) {
        sm += ssum[c]; mx = fmaxf(mx, smax[c]);
        int cnt = end - start;
        pooled[g * 302 + c]       = sm;
        pooled[g * 302 + 100 + c] = sm / fmaxf((float)cnt, 1.f);
        pooled[g * 302 + 200 + c] = mx;   // h>=0 so zero-init max == where(cnt>0,.)
    }
    if (threadIdx.x == 0) {
        const int isf = *flag;
        float u0 = isf ? ((const float*)u)[g * 2]     : bf2f(((const u16*)u)[g * 2]);
        float u1 = isf ? ((const float*)u)[g * 2 + 1] : bf2f(((const u16*)u)[g * 2 + 1]);
        pooled[g * 302 + 300] = u0;
        pooled[g * 302 + 301] = u1;
    }
}

// ---------------------------------------------------------------------------
// final 302 -> 100 -> 100 -> 2 MLP, one block per graph, fp32.
// Output dtype follows the detected input dtype.
// ---------------------------------------------------------------------------
__global__ __launch_bounds__(128)
void final_mlp(const float* __restrict__ pooled, const int* __restrict__ flag,
               const void* __restrict__ w1, const void* __restrict__ b1,
               const void* __restrict__ w2, const void* __restrict__ b2,
               const void* __restrict__ w3, const void* __restrict__ b3,
               void* __restrict__ out)
{
    const int g = blockIdx.x, t = threadIdx.x;
    const int isf = *flag;
    __shared__ float P[302], T1[100], T2[100];

    auto body = [&](auto LD) {
        for (int i = t; i < 302; i += 128) P[i] = pooled[g * 302 + i];
        __syncthreads();
        if (t < 100) {
            float a = LD(b1, t);
            for (int i = 0; i < 302; ++i) a = fmaf(P[i], LD(w1, i * 100 + t), a);
            T1[t] = fmaxf(a, 0.f);
        }
        __syncthreads();
        if (t < 100) {
            float a = LD(b2, t);
            for (int i = 0; i < 100; ++i) a = fmaf(T1[i], LD(w2, i * 100 + t), a);
            T2[t] = fmaxf(a, 0.f);
        }
        __syncthreads();
        if (t < 2) {
            float a = LD(b3, t);
            for (int i = 0; i < 100; ++i) a = fmaf(T2[i], LD(w3, i * 2 + t), a);
            if (isf) ((float*)out)[g * 2 + t] = a;
            else     ((u16*)out)[g * 2 + t]   = f2bf(a);
        }
    };

    if (isf) body([](const void* p, int i) -> float { return ((const float*)p)[i]; });
    else     body([](const void* p, int i) -> float { return bf2f(((const u16*)p)[i]); });
}

// ---------------------------------------------------------------------------
extern "C" void kernel_launch(void* const* d_in, const int* in_sizes, int n_in,
                              void* d_out, int out_size, void* d_ws, size_t ws_size,
                              hipStream_t stream)
{
    const void* x    = d_in[0];
    const int* ei    = (const int*)d_in[1];
    const int* batch = (const int*)d_in[2];
    const void* uu   = d_in[3];
    const void *l0w1 = d_in[4],  *l0b1 = d_in[5];
    const void *l0w2 = d_in[6],  *l0b2 = d_in[7];
    const void *l0w3 = d_in[8],  *l0b3 = d_in[9];
    const void *l1w1 = d_in[10], *l1b1 = d_in[11];
    const void *l1w2 = d_in[12], *l1b2 = d_in[13];
    const void *l1w3 = d_in[14], *l1b3 = d_in[15];
    const void *lw1  = d_in[16], *lb1  = d_in[17];
    const void *lw2  = d_in[18], *lb2  = d_in[19];
    const void *lw3  = d_in[20], *lb3  = d_in[21];

    char* w = (char*)d_ws;
    float* agg0   = (float*)(w);                    // 20,000,000 B
    float* agg1   = (float*)(w + 20000000);         // 20,000,000 B
    float* pooled = (float*)(w + 40000000);         //     77,312 B
    int*   flag   = (int*)  (w + 40080000);         //          4 B (~38.3 MiB total)

    ModelGNN_35304631174019_kernel<<<9766, 256, 0, stream>>>(
        (float4*)d_ws, (const u16*)x, flag);
    edge_scalar<<<E_ / EPB, 320, 0, stream>>>(1, flag, x, nullptr, ei,
                                              l0w1, l0b1, l0w2, l0b2, l0w3, l0b3, agg0);
    edge_scalar<<<E_ / EPB, 320, 0, stream>>>(0, flag, nullptr, agg0, ei,
                                              l1w1, l1b1, l1w2, l1b2, l1w3, l1b3, agg1);
    pool<<<G_, 256, 0, stream>>>(agg1, batch, uu, flag, pooled);
    final_mlp<<<G_, 128, 0, stream>>>(pooled, flag, lw1, lb1, lw2, lb2, lw3, lb3, d_out);
}

// Round 5
// 6194.307 us; speedup vs baseline: 1.1454x; 1.1454x over previous
//
#include <hip/hip_runtime.h>

typedef unsigned short u16;
#define DI __device__ __forceinline__

constexpr int N_ = 50000;
constexpr int E_ = 400000;
constexpr int G_ = 64;
constexpr int EPB = 16;         // edges per block in edge_mlp

// ---------------------------------------------------------------------------
// Named kernel (kept from the working r4 structure): zeroes agg0+agg1 (40 MB).
// Runs every launch (harness re-poisons d_ws to 0xAA before every call).
// ---------------------------------------------------------------------------
__global__ __launch_bounds__(256)
void ModelGNN_35304631174019_kernel(float4* __restrict__ aggz)
{
    int i = blockIdx.x * 256 + threadIdx.x;
    if (i < 2500000) aggz[i] = make_float4(0.f, 0.f, 0.f, 0.f);
}

// ---------------------------------------------------------------------------
// One dense layer K -> 300 with relu, for 16 edges resident in LDS.
// Thread t (< 300) owns output channel t for all 16 edges.
// k unrolled by 4 with float4 broadcast LDS reads; 16 independent accs.
// Weight layout is the ORIGINAL W[k*300 + t] (coalesced across t).
// ---------------------------------------------------------------------------
template<int K>
DI void layer300(float (*src)[304], const float* __restrict__ W,
                 const float* __restrict__ B, int t, float (*dst)[304])
{
    float acc[EPB];
    const float b = B[t];
    #pragma unroll
    for (int e = 0; e < EPB; ++e) acc[e] = b;

    for (int kk = 0; kk < (K & ~3); kk += 4) {
        const float w0 = W[(kk + 0) * 300 + t];
        const float w1 = W[(kk + 1) * 300 + t];
        const float w2 = W[(kk + 2) * 300 + t];
        const float w3 = W[(kk + 3) * 300 + t];
        #pragma unroll
        for (int e = 0; e < EPB; ++e) {
            float4 h = *(const float4*)&src[e][kk];   // 16B broadcast LDS read
            acc[e] = fmaf(h.x, w0, acc[e]);
            acc[e] = fmaf(h.y, w1, acc[e]);
            acc[e] = fmaf(h.z, w2, acc[e]);
            acc[e] = fmaf(h.w, w3, acc[e]);
        }
    }
    for (int k = (K & ~3); k < K; ++k) {              // tail (K=14 -> k=12,13)
        const float wv = W[k * 300 + t];
        #pragma unroll
        for (int e = 0; e < EPB; ++e) acc[e] = fmaf(src[e][k], wv, acc[e]);
    }
    #pragma unroll
    for (int e = 0; e < EPB; ++e) dst[e][t] = fmaxf(acc[e], 0.f);
}

// ---------------------------------------------------------------------------
// edge_mlp: fused per-edge 3-layer MLP + clamped scatter-max, fp32.
// 320 threads, 16 edges per block. BUF is unioned (IN for layer A, H2 after).
// FIRST=1: in = [xi(7) | xj-xi(7)], K1=14.   FIRST=0: [hi | hj-hi], K1=200.
// relu(where(cnt>0,segmax,0)) == int atomicMax of relu'd msgs into 0-init buf.
// ---------------------------------------------------------------------------
template<int FIRST>
__global__ __launch_bounds__(320)
void edge_mlp(const float* __restrict__ X, const int* __restrict__ ei,
              const float* __restrict__ W1, const float* __restrict__ B1,
              const float* __restrict__ W2, const float* __restrict__ B2,
              const float* __restrict__ W3, const float* __restrict__ B3,
              float* __restrict__ agg)
{
    constexpr int K1 = FIRST ? 14 : 200;
    __shared__ __align__(16) float BUF[EPB][304];   // IN (layer A), then H2
    __shared__ __align__(16) float H1[EPB][304];    // 38,912 B total -> 4 blk/CU

    const int t  = threadIdx.x;
    const int e0 = blockIdx.x * EPB;

    // ---- gather [xi | xj - xi] rows into BUF
    for (int idx = t; idx < EPB * K1; idx += 320) {
        int e   = idx / K1, k = idx - e * K1;
        int dst = ei[E_ + e0 + e];          // x_i (target)
        int src = ei[e0 + e];               // x_j (source)
        float v;
        if (FIRST) v = (k < 7)   ? X[dst * 7 + k]
                                 : X[src * 7 + (k - 7)]     - X[dst * 7 + (k - 7)];
        else       v = (k < 100) ? X[dst * 100 + k]
                                 : X[src * 100 + (k - 100)] - X[dst * 100 + (k - 100)];
        BUF[e][k] = v;
    }
    __syncthreads();

    if (t < 300) layer300<K1>(BUF, W1, B1, t, H1);    // layer A -> H1 (relu)
    __syncthreads();
    if (t < 300) layer300<300>(H1, W2, B2, t, BUF);   // layer B -> H2 (relu)
    __syncthreads();

    // ---- layer C: 300 -> 100, clamp >=0, scatter-max. 2 groups x 8 edges.
    if (t < 200) {
        const int ch = (t < 100) ? t : t - 100;
        const int eb = (t < 100) ? 0 : 8;
        float acc[8];
        const float b = B3[ch];
        #pragma unroll
        for (int i = 0; i < 8; ++i) acc[i] = b;
        for (int kk = 0; kk < 300; kk += 4) {
            const float w0 = W3[(kk + 0) * 100 + ch];
            const float w1 = W3[(kk + 1) * 100 + ch];
            const float w2 = W3[(kk + 2) * 100 + ch];
            const float w3 = W3[(kk + 3) * 100 + ch];
            #pragma unroll
            for (int i = 0; i < 8; ++i) {
                float4 h = *(const float4*)&BUF[eb + i][kk];
                acc[i] = fmaf(h.x, w0, acc[i]);
                acc[i] = fmaf(h.y, w1, acc[i]);
                acc[i] = fmaf(h.z, w2, acc[i]);
                acc[i] = fmaf(h.w, w3, acc[i]);
            }
        }
        #pragma unroll
        for (int i = 0; i < 8; ++i) {
            int dst = ei[E_ + e0 + eb + i];
            float v = fmaxf(acc[i], 0.f);   // msgs clamped: zero-init max == where(cnt>0,.)
            atomicMax((int*)(agg + (size_t)dst * 100 + ch), __float_as_int(v));
        }
    }
}

// ---------------------------------------------------------------------------
// pool: one block per graph (batch sorted -> binary-search bounds).
// pooled[g] = [addp(100) | meanp(100) | maxp(100) | u(2)]
// ---------------------------------------------------------------------------
__global__ __launch_bounds__(256)
void pool(const float* __restrict__ agg1, const int* __restrict__ batch,
          const float* __restrict__ u, float* __restrict__ pooled)
{
    const int g = blockIdx.x;
    int lo = 0, hi = N_;
    while (lo < hi) { int mid = (lo + hi) >> 1; if (batch[mid] < g) lo = mid + 1; else hi = mid; }
    const int start = lo;
    int lo2 = start, hi2 = N_;
    while (lo2 < hi2) { int mid = (lo2 + hi2) >> 1; if (batch[mid] < g + 1) lo2 = mid + 1; else hi2 = mid; }
    const int end = lo2;

    const int c = threadIdx.x & 127, half = threadIdx.x >> 7;
    float sm = 0.f, mx = 0.f;
    if (c < 100)
        for (int n = start + half; n < end; n += 2) {
            float v = agg1[(size_t)n * 100 + c];
            sm += v; mx = fmaxf(mx, v);
        }
    __shared__ float ssum[128], smax[128];
    if (half) { ssum[c] = sm; smax[c] = mx; }
    __syncthreads();
    if (!half && c < 100) {
        sm += ssum[c]; mx = fmaxf(mx, smax[c]);
        int cnt = end - start;
        pooled[g * 302 + c]       = sm;
        pooled[g * 302 + 100 + c] = sm / fmaxf((float)cnt, 1.f);
        pooled[g * 302 + 200 + c] = mx;   // h>=0 so zero-init max == where(cnt>0,.)
    }
    if (threadIdx.x == 0) {
        pooled[g * 302 + 300] = u[g * 2];
        pooled[g * 302 + 301] = u[g * 2 + 1];
    }
}

// ---------------------------------------------------------------------------
// final 302 -> 100 -> 100 -> 2 MLP, one block per graph, fp32
// ---------------------------------------------------------------------------
__global__ __launch_bounds__(128)
void final_mlp(const float* __restrict__ pooled,
               const float* __restrict__ w1, const float* __restrict__ b1,
               const float* __restrict__ w2, const float* __restrict__ b2,
               const float* __restrict__ w3, const float* __restrict__ b3,
               float* __restrict__ out)
{
    const int g = blockIdx.x, t = threadIdx.x;
    __shared__ float P[302], T1[100], T2[100];
    for (int i = t; i < 302; i += 128) P[i] = pooled[g * 302 + i];
    __syncthreads();
    if (t < 100) {
        float a = b1[t];
        for (int i = 0; i < 302; ++i) a = fmaf(P[i], w1[i * 100 + t], a);
        T1[t] = fmaxf(a, 0.f);
    }
    __syncthreads();
    if (t < 100) {
        float a = b2[t];
        for (int i = 0; i < 100; ++i) a = fmaf(T1[i], w2[i * 100 + t], a);
        T2[t] = fmaxf(a, 0.f);
    }
    __syncthreads();
    if (t < 2) {
        float a = b3[t];
        for (int i = 0; i < 100; ++i) a = fmaf(T2[i], w3[i * 2 + t], a);
        out[g * 2 + t] = a;
    }
}

// ---------------------------------------------------------------------------
extern "C" void kernel_launch(void* const* d_in, const int* in_sizes, int n_in,
                              void* d_out, int out_size, void* d_ws, size_t ws_size,
                              hipStream_t stream)
{
    const float* x     = (const float*)d_in[0];
    const int*   ei    = (const int*)d_in[1];
    const int*   batch = (const int*)d_in[2];
    const float* uu    = (const float*)d_in[3];
    const float *l0w1 = (const float*)d_in[4],  *l0b1 = (const float*)d_in[5];
    const float *l0w2 = (const float*)d_in[6],  *l0b2 = (const float*)d_in[7];
    const float *l0w3 = (const float*)d_in[8],  *l0b3 = (const float*)d_in[9];
    const float *l1w1 = (const float*)d_in[10], *l1b1 = (const float*)d_in[11];
    const float *l1w2 = (const float*)d_in[12], *l1b2 = (const float*)d_in[13];
    const float *l1w3 = (const float*)d_in[14], *l1b3 = (const float*)d_in[15];
    const float *lw1  = (const float*)d_in[16], *lb1  = (const float*)d_in[17];
    const float *lw2  = (const float*)d_in[18], *lb2  = (const float*)d_in[19];
    const float *lw3  = (const float*)d_in[20], *lb3  = (const float*)d_in[21];

    char* w = (char*)d_ws;
    float* agg0   = (float*)(w);                    // 20,000,000 B
    float* agg1   = (float*)(w + 20000000);         // 20,000,000 B
    float* pooled = (float*)(w + 40000000);         //     77,312 B (~38.3 MiB total)

    ModelGNN_35304631174019_kernel<<<9766, 256, 0, stream>>>((float4*)d_ws);
    edge_mlp<1><<<E_ / EPB, 320, 0, stream>>>(x, ei,
                                              l0w1, l0b1, l0w2, l0b2, l0w3, l0b3, agg0);
    edge_mlp<0><<<E_ / EPB, 320, 0, stream>>>(agg0, ei,
                                              l1w1, l1b1, l1w2, l1b2, l1w3, l1b3, agg1);
    pool<<<G_, 256, 0, stream>>>(agg1, batch, uu, pooled);
    final_mlp<<<G_, 128, 0, stream>>>(pooled, lw1, lb1, lw2, lb2, lw3, lb3, (float*)d_out);
}

// Round 6
// 5521.869 us; speedup vs baseline: 1.2848x; 1.1218x over previous
//
#include <hip/hip_runtime.h>

#define DI __device__ __forceinline__

constexpr int N_ = 50000;
constexpr int E_ = 400000;
constexpr int G_ = 64;
constexpr int EPB = 16;         // edges per block in edge_mlp

// ---------------------------------------------------------------------------
// Named kernel: zeroes agg0+agg1 (40 MB). Runs every launch (d_ws re-poisoned).
// ---------------------------------------------------------------------------
__global__ __launch_bounds__(256)
void ModelGNN_35304631174019_kernel(float4* __restrict__ aggz)
{
    int i = blockIdx.x * 256 + threadIdx.x;
    if (i < 2500000) aggz[i] = make_float4(0.f, 0.f, 0.f, 0.f);
}

DI void fma4(float4& a, float s, const float4 w)
{
    a.x = fmaf(s, w.x, a.x);
    a.y = fmaf(s, w.y, a.y);
    a.z = fmaf(s, w.z, a.z);
    a.w = fmaf(s, w.w, a.w);
}

// ---------------------------------------------------------------------------
// Register-tiled dense layer: NE edges x 4 channels per thread.
// Per 4-k chunk: NE ds_read_b128 (broadcast within wave) + 4 coalesced float4
// weight loads + 16*NE FMAs  ->  FMA:LDS = 16:1.
// W layout is the ORIGINAL W[k*NC + c] (float4 over c, coalesced across cg).
// ---------------------------------------------------------------------------
template<int K, int NC, int NE>
DI void tile_layer(const float (*src)[304], const float* __restrict__ W,
                   const float* __restrict__ B, int c0, int eb, float4* acc)
{
    const float4 bv = *(const float4*)(B + c0);
    #pragma unroll
    for (int i = 0; i < NE; ++i) acc[i] = bv;

    const float* wp = W + c0;
    int kk = 0;
    for (; kk + 4 <= K; kk += 4) {
        const float4 w0 = *(const float4*)(wp);
        const float4 w1 = *(const float4*)(wp + NC);
        const float4 w2 = *(const float4*)(wp + 2 * NC);
        const float4 w3 = *(const float4*)(wp + 3 * NC);
        wp += 4 * NC;
        #pragma unroll
        for (int i = 0; i < NE; ++i) {
            const float4 h = *(const float4*)&src[eb + i][kk];   // ds_read_b128
            fma4(acc[i], h.x, w0);
            fma4(acc[i], h.y, w1);
            fma4(acc[i], h.z, w2);
            fma4(acc[i], h.w, w3);
        }
    }
    for (; kk < K; ++kk) {                      // tail (K=14 -> k=12,13)
        const float4 w0 = *(const float4*)(wp);
        wp += NC;
        #pragma unroll
        for (int i = 0; i < NE; ++i) fma4(acc[i], src[eb + i][kk], w0);
    }
}

// ---------------------------------------------------------------------------
// edge_mlp: fused per-edge 3-layer MLP + clamped scatter-max, fp32.
// 320 threads, 16 edges per block. BUF unioned (IN for layer A, H2 after B).
// Layers A/B: 300 threads, 4ch x 4e tiles (cg=t%75, eg=t/75).
// Layer  C  : 200 threads, 4ch x 2e tiles (cg=t%25, eg=t/25).
// relu(where(cnt>0,segmax,0)) == int atomicMax of relu'd msgs into 0-init buf.
// ---------------------------------------------------------------------------
template<int FIRST>
__global__ __launch_bounds__(320)
void edge_mlp(const float* __restrict__ X, const int* __restrict__ ei,
              const float* __restrict__ W1, const float* __restrict__ B1,
              const float* __restrict__ W2, const float* __restrict__ B2,
              const float* __restrict__ W3, const float* __restrict__ B3,
              float* __restrict__ agg)
{
    constexpr int K1 = FIRST ? 14 : 200;
    __shared__ __align__(16) float BUF[EPB][304];   // IN (layer A), then H2
    __shared__ __align__(16) float H1[EPB][304];    // 38,912 B total

    const int t  = threadIdx.x;
    const int e0 = blockIdx.x * EPB;

    // ---- gather [xi | xj - xi] rows into BUF
    for (int idx = t; idx < EPB * K1; idx += 320) {
        int e   = idx / K1, k = idx - e * K1;
        int dst = ei[E_ + e0 + e];          // x_i (target)
        int src = ei[e0 + e];               // x_j (source)
        float v;
        if (FIRST) v = (k < 7)   ? X[dst * 7 + k]
                                 : X[src * 7 + (k - 7)]     - X[dst * 7 + (k - 7)];
        else       v = (k < 100) ? X[dst * 100 + k]
                                 : X[src * 100 + (k - 100)] - X[dst * 100 + (k - 100)];
        BUF[e][k] = v;
    }
    __syncthreads();

    // ---- layer A: K1 -> 300, relu, into H1
    if (t < 300) {
        const int c0 = (t % 75) * 4, eb = (t / 75) * 4;
        float4 acc[4];
        tile_layer<K1, 300, 4>(BUF, W1, B1, c0, eb, acc);
        #pragma unroll
        for (int i = 0; i < 4; ++i) {
            float4 r = acc[i];
            *(float4*)&H1[eb + i][c0] = make_float4(fmaxf(r.x, 0.f), fmaxf(r.y, 0.f),
                                                    fmaxf(r.z, 0.f), fmaxf(r.w, 0.f));
        }
    }
    __syncthreads();

    // ---- layer B: 300 -> 300, relu, into BUF
    if (t < 300) {
        const int c0 = (t % 75) * 4, eb = (t / 75) * 4;
        float4 acc[4];
        tile_layer<300, 300, 4>(H1, W2, B2, c0, eb, acc);
        #pragma unroll
        for (int i = 0; i < 4; ++i) {
            float4 r = acc[i];
            *(float4*)&BUF[eb + i][c0] = make_float4(fmaxf(r.x, 0.f), fmaxf(r.y, 0.f),
                                                     fmaxf(r.z, 0.f), fmaxf(r.w, 0.f));
        }
    }
    __syncthreads();

    // ---- layer C: 300 -> 100, clamp >=0, scatter-max
    if (t < 200) {
        const int c0 = (t % 25) * 4, eb = (t / 25) * 2;
        float4 acc[2];
        tile_layer<300, 100, 2>(BUF, W3, B3, c0, eb, acc);
        #pragma unroll
        for (int i = 0; i < 2; ++i) {
            const int dst = ei[E_ + e0 + eb + i];
            int* base = (int*)(agg + (size_t)dst * 100 + c0);
            // msgs clamped to >=0: zero-init max == relu(where(cnt>0, segmax, 0))
            atomicMax(base + 0, __float_as_int(fmaxf(acc[i].x, 0.f)));
            atomicMax(base + 1, __float_as_int(fmaxf(acc[i].y, 0.f)));
            atomicMax(base + 2, __float_as_int(fmaxf(acc[i].z, 0.f)));
            atomicMax(base + 3, __float_as_int(fmaxf(acc[i].w, 0.f)));
        }
    }
}

// ---------------------------------------------------------------------------
// pool: one block per graph (batch sorted -> binary-search bounds).
// pooled[g] = [addp(100) | meanp(100) | maxp(100) | u(2)]
// ---------------------------------------------------------------------------
__global__ __launch_bounds__(256)
void pool(const float* __restrict__ agg1, const int* __restrict__ batch,
          const float* __restrict__ u, float* __restrict__ pooled)
{
    const int g = blockIdx.x;
    int lo = 0, hi = N_;
    while (lo < hi) { int mid = (lo + hi) >> 1; if (batch[mid] < g) lo = mid + 1; else hi = mid; }
    const int start = lo;
    int lo2 = start, hi2 = N_;
    while (lo2 < hi2) { int mid = (lo2 + hi2) >> 1; if (batch[mid] < g + 1) lo2 = mid + 1; else hi2 = mid; }
    const int end = lo2;

    const int c = threadIdx.x & 127, half = threadIdx.x >> 7;
    float sm = 0.f, mx = 0.f;
    if (c < 100)
        for (int n = start + half; n < end; n += 2) {
            float v = agg1[(size_t)n * 100 + c];
            sm += v; mx = fmaxf(mx, v);
        }
    __shared__ float ssum[128], smax[128];
    if (half) { ssum[c] = sm; smax[c] = mx; }
    __syncthreads();
    if (!half && c < 100) {
        sm += ssum[c]; mx = fmaxf(mx, smax[c]);
        int cnt = end - start;
        pooled[g * 302 + c]       = sm;
        pooled[g * 302 + 100 + c] = sm / fmaxf((float)cnt, 1.f);
        pooled[g * 302 + 200 + c] = mx;   // h>=0 so zero-init max == where(cnt>0,.)
    }
    if (threadIdx.x == 0) {
        pooled[g * 302 + 300] = u[g * 2];
        pooled[g * 302 + 301] = u[g * 2 + 1];
    }
}

// ---------------------------------------------------------------------------
// final 302 -> 100 -> 100 -> 2 MLP, one block per graph, fp32
// ---------------------------------------------------------------------------
__global__ __launch_bounds__(128)
void final_mlp(const float* __restrict__ pooled,
               const float* __restrict__ w1, const float* __restrict__ b1,
               const float* __restrict__ w2, const float* __restrict__ b2,
               const float* __restrict__ w3, const float* __restrict__ b3,
               float* __restrict__ out)
{
    const int g = blockIdx.x, t = threadIdx.x;
    __shared__ float P[302], T1[100], T2[100];
    for (int i = t; i < 302; i += 128) P[i] = pooled[g * 302 + i];
    __syncthreads();
    if (t < 100) {
        float a = b1[t];
        for (int i = 0; i < 302; ++i) a = fmaf(P[i], w1[i * 100 + t], a);
        T1[t] = fmaxf(a, 0.f);
    }
    __syncthreads();
    if (t < 100) {
        float a = b2[t];
        for (int i = 0; i < 100; ++i) a = fmaf(T1[i], w2[i * 100 + t], a);
        T2[t] = fmaxf(a, 0.f);
    }
    __syncthreads();
    if (t < 2) {
        float a = b3[t];
        for (int i = 0; i < 100; ++i) a = fmaf(T2[i], w3[i * 2 + t], a);
        out[g * 2 + t] = a;
    }
}

// ---------------------------------------------------------------------------
extern "C" void kernel_launch(void* const* d_in, const int* in_sizes, int n_in,
                              void* d_out, int out_size, void* d_ws, size_t ws_size,
                              hipStream_t stream)
{
    const float* x     = (const float*)d_in[0];
    const int*   ei    = (const int*)d_in[1];
    const int*   batch = (const int*)d_in[2];
    const float* uu    = (const float*)d_in[3];
    const float *l0w1 = (const float*)d_in[4],  *l0b1 = (const float*)d_in[5];
    const float *l0w2 = (const float*)d_in[6],  *l0b2 = (const float*)d_in[7];
    const float *l0w3 = (const float*)d_in[8],  *l0b3 = (const float*)d_in[9];
    const float *l1w1 = (const float*)d_in[10], *l1b1 = (const float*)d_in[11];
    const float *l1w2 = (const float*)d_in[12], *l1b2 = (const float*)d_in[13];
    const float *l1w3 = (const float*)d_in[14], *l1b3 = (const float*)d_in[15];
    const float *lw1  = (const float*)d_in[16], *lb1  = (const float*)d_in[17];
    const float *lw2  = (const float*)d_in[18], *lb2  = (const float*)d_in[19];
    const float *lw3  = (const float*)d_in[20], *lb3  = (const float*)d_in[21];

    char* w = (char*)d_ws;
    float* agg0   = (float*)(w);                    // 20,000,000 B
    float* agg1   = (float*)(w + 20000000);         // 20,000,000 B
    float* pooled = (float*)(w + 40000000);         //     77,312 B (~38.3 MiB total)

    ModelGNN_35304631174019_kernel<<<9766, 256, 0, stream>>>((float4*)d_ws);
    edge_mlp<1><<<E_ / EPB, 320, 0, stream>>>(x, ei,
                                              l0w1, l0b1, l0w2, l0b2, l0w3, l0b3, agg0);
    edge_mlp<0><<<E_ / EPB, 320, 0, stream>>>(agg0, ei,
                                              l1w1, l1b1, l1w2, l1b2, l1w3, l1b3, agg1);
    pool<<<G_, 256, 0, stream>>>(agg1, batch, uu, pooled);
    final_mlp<<<G_, 128, 0, stream>>>(pooled, lw1, lb1, lw2, lb2, lw3, lb3, (float*)d_out);
}

// Round 7
// 2254.852 us; speedup vs baseline: 3.1464x; 2.4489x over previous
//
#include <hip/hip_runtime.h>

typedef unsigned short u16;
typedef short s16x8 __attribute__((ext_vector_type(8)));   // 8 bf16 bit-patterns
typedef float f32x4 __attribute__((ext_vector_type(4)));

#define DI __device__ __forceinline__

constexpr int N_ = 50000;
constexpr int E_ = 400000;
constexpr int G_ = 64;

DI u16 f2bf(float f) {
    union { unsigned u; float f; } c; c.f = f;
    unsigned u = c.u;
    u += 0x7fffu + ((u >> 16) & 1u);   // RNE
    return (u16)(u >> 16);
}

DI s16x8 ldv(const u16* p) { return *(const s16x8*)p; }
DI f32x4 MFMA(s16x8 a, s16x8 b, f32x4 c) {
    return __builtin_amdgcn_mfma_f32_16x16x32_bf16(a, b, c, 0, 0, 0);
}

// ---------------------------------------------------------------------------
// Named kernel (symbol required by harness — r3/r4 bisection): zero agg0+agg1
// (40 MB) and repack/transpose/pad all edge-MLP weights f32 -> bf16 Wt[n][k],
// folding the [xi, xj-xi] -> [xi, xj] transform:
//   [xi, xj-xi] @ W = xi @ (W_a - W_b) + xj @ W_b
// ---------------------------------------------------------------------------
__global__ __launch_bounds__(256)
void ModelGNN_35304631174019_kernel(
          const float* __restrict__ l0w1, const float* __restrict__ l0w2,
          const float* __restrict__ l0w3, const float* __restrict__ l1w1,
          const float* __restrict__ l1w2, const float* __restrict__ l1w3,
          float4* __restrict__ aggz,
          u16* __restrict__ wt0, u16* __restrict__ wt1,
          u16* __restrict__ wt2a, u16* __restrict__ wt2b,
          u16* __restrict__ wt3a, u16* __restrict__ wt3b)
{
    int i = blockIdx.x * 256 + threadIdx.x;
    if (i < 2500000) { aggz[i] = make_float4(0.f, 0.f, 0.f, 0.f); return; }  // agg0+agg1
    int j = i - 2500000;
    if (j < 10240) {                       // wt0 [320][32]  from l0_w1 [14][300]
        int n = j >> 5, k = j & 31;
        u16 v = 0;
        if (n < 300) {
            if (k < 7) v = f2bf(l0w1[k * 300 + n] - l0w1[(7 + k) * 300 + n]);
            else if (k >= 16 && k < 23) v = f2bf(l0w1[(7 + (k - 16)) * 300 + n]);
        }
        wt0[j] = v; return;
    }
    j -= 10240;
    if (j < 71680) {                       // wt1 [320][224] from l1_w1 [200][300]
        int n = j / 224, k = j - n * 224;
        u16 v = 0;
        if (n < 300) {
            if (k < 100) v = f2bf(l1w1[k * 300 + n] - l1w1[(100 + k) * 300 + n]);
            else if (k >= 112 && k < 212) v = f2bf(l1w1[(100 + (k - 112)) * 300 + n]);
        }
        wt1[j] = v; return;
    }
    j -= 71680;
    if (j < 102400) { int n = j / 320, k = j - n * 320; wt2a[j] = (n < 300 && k < 300) ? f2bf(l0w2[k * 300 + n]) : (u16)0; return; }
    j -= 102400;
    if (j < 102400) { int n = j / 320, k = j - n * 320; wt2b[j] = (n < 300 && k < 300) ? f2bf(l1w2[k * 300 + n]) : (u16)0; return; }
    j -= 102400;
    if (j < 35840)  { int n = j / 320, k = j - n * 320; wt3a[j] = (n < 100 && k < 300) ? f2bf(l0w3[k * 100 + n]) : (u16)0; return; }
    j -= 35840;
    if (j < 35840)  { int n = j / 320, k = j - n * 320; wt3b[j] = (n < 100 && k < 300) ? f2bf(l1w3[k * 100 + n]) : (u16)0; return; }
}

// ---------------------------------------------------------------------------
// edge_mlp: fused per-edge 3-layer MLP + clamped scatter-max via MFMA.
// One wave = 16 edges. GEMM1 -> H1 (LDS bf16, stride 328 = conflict-free b128),
// GEMM2 fused with GEMM3 in 32-wide K-chunks (H2 chunk in LDS [16][40]).
// Layouts (m89/m120-verified): A: m=lane&15, k=quad*8+j ; B: n=lane&15,
// k=quad*8+j (weights pre-transposed) ; C/D: col=lane&15, row=quad*4+reg.
// relu(where(cnt>0,segmax,0)) == int atomicMax of relu'd msgs into 0-init buf.
// ---------------------------------------------------------------------------
template<bool FIRST>
__global__ __launch_bounds__(256)
void edge_mlp(const float* __restrict__ X, const float* __restrict__ H0,
              const int* __restrict__ ei,
              const u16* __restrict__ W1, const float* __restrict__ B1,
              const u16* __restrict__ W2, const float* __restrict__ B2,
              const u16* __restrict__ W3, const float* __restrict__ B3,
              float* __restrict__ agg)
{
    constexpr int KP = FIRST ? 32 : 224;
    constexpr int KA = KP / 32;
    __shared__ __align__(16) u16 H1s[4 * 16 * 328];   // 41,984 B
    __shared__ __align__(16) u16 SCR[4 * 16 * 40];    //  5,120 B

    const int tid  = threadIdx.x;
    const int wave = tid >> 6, lane = tid & 63;
    const int col  = lane & 15, kq = lane >> 4;
    const int ebase = blockIdx.x * 64 + wave * 16;

    u16* H1w = H1s + wave * (16 * 328);
    u16* SCw = SCR + wave * (16 * 40);

    s16x8 aF[KA];
    if constexpr (FIRST) {
        // gather [xi | xj] into SCw as bf16 IN[16][40] (K padded to 32)
        for (int s = lane; s < 16 * 32; s += 64) {
            int e = s >> 5, k = s & 31;
            u16 v = 0;
            if (k < 7)                  v = f2bf(X[(size_t)ei[E_ + ebase + e] * 7 + k]);
            else if (k >= 16 && k < 23) v = f2bf(X[(size_t)ei[ebase + e] * 7 + (k - 16)]);
            SCw[e * 40 + k] = v;
        }
        __syncthreads();
        #pragma unroll
        for (int s = 0; s < KA; ++s) aF[s] = ldv(SCw + col * 40 + s * 32 + kq * 8);
    } else {
        // build A-fragments directly from global agg0 (h0, f32 -> bf16)
        const int dn = ei[E_ + ebase + col];   // dst node (x_i) of this lane's edge
        const int sn = ei[ebase + col];        // src node (x_j)
        #pragma unroll
        for (int s = 0; s < KA; ++s) {
            int b = s * 4 + kq;                // 8-elem k-group, 0..27; k = 8b+j
            int node = (b < 14) ? dn : sn;
            int c = ((b < 14) ? b : b - 14) * 8;
            s16x8 t = {0, 0, 0, 0, 0, 0, 0, 0};
            if (c < 104) {
                const float* r = H0 + (size_t)node * 100 + c;
                float4 lo = *(const float4*)r;
                t[0] = (short)f2bf(lo.x); t[1] = (short)f2bf(lo.y);
                t[2] = (short)f2bf(lo.z); t[3] = (short)f2bf(lo.w);
                if (c < 96) {
                    float4 hi = *(const float4*)(r + 4);
                    t[4] = (short)f2bf(hi.x); t[5] = (short)f2bf(hi.y);
                    t[6] = (short)f2bf(hi.z); t[7] = (short)f2bf(hi.w);
                }
            }
            aF[s] = t;
        }
    }

    // GEMM1: [16,KP] x Wt1[320,KP]^T -> H1[16][320] (relu, bf16)
    #pragma unroll 1
    for (int t2 = 0; t2 < 10; ++t2) {
        const int n0 = t2 * 32;
        f32x4 z = {0.f, 0.f, 0.f, 0.f};
        f32x4 ac0 = z, ac1 = z;
        const u16* w0 = W1 + (size_t)(n0 + col) * KP + kq * 8;
        #pragma unroll
        for (int s = 0; s < KA; ++s) {
            s16x8 b0 = ldv(w0 + s * 32);
            s16x8 b1 = ldv(w0 + 16 * KP + s * 32);
            ac0 = MFMA(aF[s], b0, ac0);
            ac1 = MFMA(aF[s], b1, ac1);
        }
        const int n = n0 + col;
        const float bi0 = (n < 300)      ? B1[n]      : 0.f;
        const float bi1 = (n + 16 < 300) ? B1[n + 16] : 0.f;
        #pragma unroll
        for (int r = 0; r < 4; ++r) {
            int row = kq * 4 + r;
            H1w[row * 328 + n]      = f2bf(fmaxf(ac0[r] + bi0, 0.f));
            H1w[row * 328 + n + 16] = f2bf(fmaxf(ac1[r] + bi1, 0.f));
        }
    }
    __syncthreads();

    // A-fragments for GEMM2: this wave's full [16 x 320] from H1 (40 VGPRs)
    s16x8 a2[10];
    #pragma unroll
    for (int s = 0; s < 10; ++s) a2[s] = ldv(H1w + col * 328 + s * 32 + kq * 8);

    f32x4 mac[7];
    #pragma unroll
    for (int u = 0; u < 7; ++u) { f32x4 z = {0.f, 0.f, 0.f, 0.f}; mac[u] = z; }

    // GEMM2 (K=320) fused with GEMM3 in 32-wide chunks of H2
    #pragma unroll 1
    for (int ch = 0; ch < 10; ++ch) {
        const int n0 = ch * 32;
        f32x4 z = {0.f, 0.f, 0.f, 0.f};
        f32x4 ac0 = z, ac1 = z;
        const u16* w0 = W2 + (size_t)(n0 + col) * 320 + kq * 8;
        #pragma unroll
        for (int s = 0; s < 10; ++s) {
            s16x8 b0 = ldv(w0 + s * 32);
            s16x8 b1 = ldv(w0 + 16 * 320 + s * 32);
            ac0 = MFMA(a2[s], b0, ac0);
            ac1 = MFMA(a2[s], b1, ac1);
        }
        __syncthreads();   // previous chunk's a3 reads done before SCw overwrite
        const int n = n0 + col;
        const float bi0 = (n < 300)      ? B2[n]      : 0.f;
        const float bi1 = (n + 16 < 300) ? B2[n + 16] : 0.f;
        #pragma unroll
        for (int r = 0; r < 4; ++r) {
            int row = kq * 4 + r;
            SCw[row * 40 + col]      = f2bf(fmaxf(ac0[r] + bi0, 0.f));
            SCw[row * 40 + col + 16] = f2bf(fmaxf(ac1[r] + bi1, 0.f));
        }
        __syncthreads();
        s16x8 a3 = ldv(SCw + col * 40 + kq * 8);
        #pragma unroll
        for (int u = 0; u < 7; ++u) {
            s16x8 b = ldv(W3 + (size_t)(u * 16 + col) * 320 + n0 + kq * 8);
            mac[u] = MFMA(a3, b, mac[u]);
        }
    }

    // scatter-max: per (u,r) instruction lanes cover 16 consecutive channels
    // x 4 edges -> coalesced atomic sectors. Msgs clamped >=0 (see header).
    const int e0 = ebase + kq * 4;
    int dsts[4];
    #pragma unroll
    for (int r = 0; r < 4; ++r) dsts[r] = ei[E_ + e0 + r];
    #pragma unroll
    for (int u = 0; u < 7; ++u) {
        int c3 = u * 16 + col;
        if (c3 < 100) {
            float bi = B3[c3];
            #pragma unroll
            for (int r = 0; r < 4; ++r) {
                float v = fmaxf(mac[u][r] + bi, 0.f);
                atomicMax((int*)(agg + (size_t)dsts[r] * 100 + c3), __float_as_int(v));
            }
        }
    }
}

// ---------------------------------------------------------------------------
// pool: one block per graph (batch sorted -> binary-search bounds).
// pooled[g] = [addp(100) | meanp(100) | maxp(100) | u(2)]
// ---------------------------------------------------------------------------
__global__ __launch_bounds__(256)
void pool(const float* __restrict__ agg1, const int* __restrict__ batch,
          const float* __restrict__ u, float* __restrict__ pooled)
{
    const int g = blockIdx.x;
    int lo = 0, hi = N_;
    while (lo < hi) { int mid = (lo + hi) >> 1; if (batch[mid] < g) lo = mid + 1; else hi = mid; }
    const int start = lo;
    int lo2 = start, hi2 = N_;
    while (lo2 < hi2) { int mid = (lo2 + hi2) >> 1; if (batch[mid] < g + 1) lo2 = mid + 1; else hi2 = mid; }
    const int end = lo2;

    const int c = threadIdx.x & 127, half = threadIdx.x >> 7;
    float sm = 0.f, mx = 0.f;
    if (c < 100)
        for (int n = start + half; n < end; n += 2) {
            float v = agg1[(size_t)n * 100 + c];
            sm += v; mx = fmaxf(mx, v);
        }
    __shared__ float ssum[128], smax[128];
    if (half) { ssum[c] = sm; smax[c] = mx; }
    __syncthreads();
    if (!half && c < 100) {
        sm += ssum[c]; mx = fmaxf(mx, smax[c]);
        int cnt = end - start;
        pooled[g * 302 + c]       = sm;
        pooled[g * 302 + 100 + c] = sm / fmaxf((float)cnt, 1.f);
        pooled[g * 302 + 200 + c] = mx;   // h>=0 so zero-init max == where(cnt>0,.)
    }
    if (threadIdx.x == 0) {
        pooled[g * 302 + 300] = u[g * 2];
        pooled[g * 302 + 301] = u[g * 2 + 1];
    }
}

// ---------------------------------------------------------------------------
// final 302 -> 100 -> 100 -> 2 MLP, one block per graph, fp32
// ---------------------------------------------------------------------------
__global__ __launch_bounds__(128)
void final_mlp(const float* __restrict__ pooled,
               const float* __restrict__ w1, const float* __restrict__ b1,
               const float* __restrict__ w2, const float* __restrict__ b2,
               const float* __restrict__ w3, const float* __restrict__ b3,
               float* __restrict__ out)
{
    const int g = blockIdx.x, t = threadIdx.x;
    __shared__ float P[302], T1[100], T2[100];
    for (int i = t; i < 302; i += 128) P[i] = pooled[g * 302 + i];
    __syncthreads();
    if (t < 100) {
        float a = b1[t];
        for (int i = 0; i < 302; ++i) a = fmaf(P[i], w1[i * 100 + t], a);
        T1[t] = fmaxf(a, 0.f);
    }
    __syncthreads();
    if (t < 100) {
        float a = b2[t];
        for (int i = 0; i < 100; ++i) a = fmaf(T1[i], w2[i * 100 + t], a);
        T2[t] = fmaxf(a, 0.f);
    }
    __syncthreads();
    if (t < 2) {
        float a = b3[t];
        for (int i = 0; i < 100; ++i) a = fmaf(T2[i], w3[i * 2 + t], a);
        out[g * 2 + t] = a;
    }
}

// ---------------------------------------------------------------------------
extern "C" void kernel_launch(void* const* d_in, const int* in_sizes, int n_in,
                              void* d_out, int out_size, void* d_ws, size_t ws_size,
                              hipStream_t stream)
{
    const float* x     = (const float*)d_in[0];
    const int*   ei    = (const int*)d_in[1];
    const int*   batch = (const int*)d_in[2];
    const float* uu    = (const float*)d_in[3];
    const float *l0w1 = (const float*)d_in[4],  *l0b1 = (const float*)d_in[5];
    const float *l0w2 = (const float*)d_in[6],  *l0b2 = (const float*)d_in[7];
    const float *l0w3 = (const float*)d_in[8],  *l0b3 = (const float*)d_in[9];
    const float *l1w1 = (const float*)d_in[10], *l1b1 = (const float*)d_in[11];
    const float *l1w2 = (const float*)d_in[12], *l1b2 = (const float*)d_in[13];
    const float *l1w3 = (const float*)d_in[14], *l1b3 = (const float*)d_in[15];
    const float *lw1  = (const float*)d_in[16], *lb1  = (const float*)d_in[17];
    const float *lw2  = (const float*)d_in[18], *lb2  = (const float*)d_in[19];
    const float *lw3  = (const float*)d_in[20], *lb3  = (const float*)d_in[21];

    char* w = (char*)d_ws;
    float* agg0   = (float*)(w);                    // 20,000,000 B
    float* agg1   = (float*)(w + 20000000);         // 20,000,000 B
    float* pooled = (float*)(w + 40000000);         //     77,312 B
    u16* wt0  = (u16*)(w + 40077312);               //     20,480 B
    u16* wt1  = (u16*)(w + 40097792);               //    143,360 B
    u16* wt2a = (u16*)(w + 40241152);               //    204,800 B
    u16* wt2b = (u16*)(w + 40445952);               //    204,800 B
    u16* wt3a = (u16*)(w + 40650752);               //     71,680 B
    u16* wt3b = (u16*)(w + 40722432);               //     71,680 B  (total ~38.9 MiB)

    ModelGNN_35304631174019_kernel<<<11166, 256, 0, stream>>>(
        l0w1, l0w2, l0w3, l1w1, l1w2, l1w3,
        (float4*)d_ws, wt0, wt1, wt2a, wt2b, wt3a, wt3b);
    edge_mlp<true ><<<6250, 256, 0, stream>>>(x, nullptr, ei, wt0, l0b1, wt2a, l0b2, wt3a, l0b3, agg0);
    edge_mlp<false><<<6250, 256, 0, stream>>>(nullptr, agg0, ei, wt1, l1b1, wt2b, l1b2, wt3b, l1b3, agg1);
    pool<<<G_, 256, 0, stream>>>(agg1, batch, uu, pooled);
    final_mlp<<<G_, 128, 0, stream>>>(pooled, lw1, lb1, lw2, lb2, lw3, lb3, (float*)d_out);
}

// Round 8
// 2093.602 us; speedup vs baseline: 3.3888x; 1.0770x over previous
//
#include <hip/hip_runtime.h>

typedef unsigned short u16;
typedef short s16x8 __attribute__((ext_vector_type(8)));   // 8 bf16 bit-patterns
typedef float f32x4 __attribute__((ext_vector_type(4)));

#define DI __device__ __forceinline__

constexpr int N_ = 50000;
constexpr int E_ = 400000;
constexpr int G_ = 64;

DI u16 f2bf(float f) {
    union { unsigned u; float f; } c; c.f = f;
    unsigned u = c.u;
    u += 0x7fffu + ((u >> 16) & 1u);   // RNE
    return (u16)(u >> 16);
}

DI s16x8 ldv(const u16* p) { return *(const s16x8*)p; }
DI f32x4 MFMA(s16x8 a, s16x8 b, f32x4 c) {
    return __builtin_amdgcn_mfma_f32_16x16x32_bf16(a, b, c, 0, 0, 0);
}

// ---------------------------------------------------------------------------
// Named kernel (symbol required by harness): zero agg0+agg1 (40 MB) and
// repack/transpose/pad all edge-MLP weights f32 -> bf16 Wt[n][k], folding
// the [xi, xj-xi] -> [xi, xj] transform:
//   [xi, xj-xi] @ W = xi @ (W_a - W_b) + xj @ W_b
// ---------------------------------------------------------------------------
__global__ __launch_bounds__(256)
void ModelGNN_35304631174019_kernel(
          const float* __restrict__ l0w1, const float* __restrict__ l0w2,
          const float* __restrict__ l0w3, const float* __restrict__ l1w1,
          const float* __restrict__ l1w2, const float* __restrict__ l1w3,
          float4* __restrict__ aggz,
          u16* __restrict__ wt0, u16* __restrict__ wt1,
          u16* __restrict__ wt2a, u16* __restrict__ wt2b,
          u16* __restrict__ wt3a, u16* __restrict__ wt3b)
{
    int i = blockIdx.x * 256 + threadIdx.x;
    if (i < 2500000) { aggz[i] = make_float4(0.f, 0.f, 0.f, 0.f); return; }  // agg0+agg1
    int j = i - 2500000;
    if (j < 10240) {                       // wt0 [320][32]  from l0_w1 [14][300]
        int n = j >> 5, k = j & 31;
        u16 v = 0;
        if (n < 300) {
            if (k < 7) v = f2bf(l0w1[k * 300 + n] - l0w1[(7 + k) * 300 + n]);
            else if (k >= 16 && k < 23) v = f2bf(l0w1[(7 + (k - 16)) * 300 + n]);
        }
        wt0[j] = v; return;
    }
    j -= 10240;
    if (j < 71680) {                       // wt1 [320][224] from l1_w1 [200][300]
        int n = j / 224, k = j - n * 224;
        u16 v = 0;
        if (n < 300) {
            if (k < 100) v = f2bf(l1w1[k * 300 + n] - l1w1[(100 + k) * 300 + n]);
            else if (k >= 112 && k < 212) v = f2bf(l1w1[(100 + (k - 112)) * 300 + n]);
        }
        wt1[j] = v; return;
    }
    j -= 71680;
    if (j < 102400) { int n = j / 320, k = j - n * 320; wt2a[j] = (n < 300 && k < 300) ? f2bf(l0w2[k * 300 + n]) : (u16)0; return; }
    j -= 102400;
    if (j < 102400) { int n = j / 320, k = j - n * 320; wt2b[j] = (n < 300 && k < 300) ? f2bf(l1w2[k * 300 + n]) : (u16)0; return; }
    j -= 102400;
    if (j < 35840)  { int n = j / 320, k = j - n * 320; wt3a[j] = (n < 100 && k < 300) ? f2bf(l0w3[k * 100 + n]) : (u16)0; return; }
    j -= 35840;
    if (j < 35840)  { int n = j / 320, k = j - n * 320; wt3b[j] = (n < 100 && k < 300) ? f2bf(l1w3[k * 100 + n]) : (u16)0; return; }
}

// ---------------------------------------------------------------------------
// edge_mlp: fused per-edge 3-layer MLP + clamped scatter-max via MFMA.
// One wave = 16 edges. ALL LDS buffers are WAVE-PRIVATE -> NO __syncthreads
// anywhere: intra-wave ds_write -> ds_read ordering is enforced by the
// compiler's lgkmcnt waits. (R7 had 22 block-wide barriers here; their
// vmcnt(0)+lgkmcnt(0) drains serialized all 4 waves -> MfmaUtil 6.5%.)
// Layouts (m89/m120-verified): A: m=lane&15, k=quad*8+j ; B: n=lane&15,
// k=quad*8+j (weights pre-transposed) ; C/D: col=lane&15, row=quad*4+reg.
// relu(where(cnt>0,segmax,0)) == int atomicMax of relu'd msgs into 0-init buf.
// ---------------------------------------------------------------------------
template<bool FIRST>
__global__ __launch_bounds__(256)
void edge_mlp(const float* __restrict__ X, const float* __restrict__ H0,
              const int* __restrict__ ei,
              const u16* __restrict__ W1, const float* __restrict__ B1,
              const u16* __restrict__ W2, const float* __restrict__ B2,
              const u16* __restrict__ W3, const float* __restrict__ B3,
              float* __restrict__ agg)
{
    constexpr int KP = FIRST ? 32 : 224;
    constexpr int KA = KP / 32;
    __shared__ __align__(16) u16 H1s[4 * 16 * 328];   // 41,984 B (wave-private slices)
    __shared__ __align__(16) u16 SCR[4 * 16 * 40];    //  5,120 B (wave-private slices)

    const int tid  = threadIdx.x;
    const int wave = tid >> 6, lane = tid & 63;
    const int col  = lane & 15, kq = lane >> 4;
    const int ebase = blockIdx.x * 64 + wave * 16;

    u16* H1w = H1s + wave * (16 * 328);
    u16* SCw = SCR + wave * (16 * 40);

    s16x8 aF[KA];
    if constexpr (FIRST) {
        // gather [xi | xj] into SCw as bf16 IN[16][40] (K padded to 32)
        for (int s = lane; s < 16 * 32; s += 64) {
            int e = s >> 5, k = s & 31;
            u16 v = 0;
            if (k < 7)                  v = f2bf(X[(size_t)ei[E_ + ebase + e] * 7 + k]);
            else if (k >= 16 && k < 23) v = f2bf(X[(size_t)ei[ebase + e] * 7 + (k - 16)]);
            SCw[e * 40 + k] = v;
        }
        // wave-private: compiler's lgkmcnt wait orders write->read
        #pragma unroll
        for (int s = 0; s < KA; ++s) aF[s] = ldv(SCw + col * 40 + s * 32 + kq * 8);
    } else {
        // build A-fragments directly from global agg0 (h0, f32 -> bf16)
        const int dn = ei[E_ + ebase + col];   // dst node (x_i) of this lane's edge
        const int sn = ei[ebase + col];        // src node (x_j)
        #pragma unroll
        for (int s = 0; s < KA; ++s) {
            int b = s * 4 + kq;                // 8-elem k-group, 0..27; k = 8b+j
            int node = (b < 14) ? dn : sn;
            int c = ((b < 14) ? b : b - 14) * 8;
            s16x8 t = {0, 0, 0, 0, 0, 0, 0, 0};
            if (c < 104) {
                const float* r = H0 + (size_t)node * 100 + c;
                float4 lo = *(const float4*)r;
                t[0] = (short)f2bf(lo.x); t[1] = (short)f2bf(lo.y);
                t[2] = (short)f2bf(lo.z); t[3] = (short)f2bf(lo.w);
                if (c < 96) {
                    float4 hi = *(const float4*)(r + 4);
                    t[4] = (short)f2bf(hi.x); t[5] = (short)f2bf(hi.y);
                    t[6] = (short)f2bf(hi.z); t[7] = (short)f2bf(hi.w);
                }
            }
            aF[s] = t;
        }
    }

    // GEMM1: [16,KP] x Wt1[320,KP]^T -> H1[16][320] (relu, bf16)
    #pragma unroll 1
    for (int t2 = 0; t2 < 10; ++t2) {
        const int n0 = t2 * 32;
        f32x4 z = {0.f, 0.f, 0.f, 0.f};
        f32x4 ac0 = z, ac1 = z;
        const u16* w0 = W1 + (size_t)(n0 + col) * KP + kq * 8;
        #pragma unroll
        for (int s = 0; s < KA; ++s) {
            s16x8 b0 = ldv(w0 + s * 32);
            s16x8 b1 = ldv(w0 + 16 * KP + s * 32);
            ac0 = MFMA(aF[s], b0, ac0);
            ac1 = MFMA(aF[s], b1, ac1);
        }
        const int n = n0 + col;
        const float bi0 = (n < 300)      ? B1[n]      : 0.f;
        const float bi1 = (n + 16 < 300) ? B1[n + 16] : 0.f;
        #pragma unroll
        for (int r = 0; r < 4; ++r) {
            int row = kq * 4 + r;
            H1w[row * 328 + n]      = f2bf(fmaxf(ac0[r] + bi0, 0.f));
            H1w[row * 328 + n + 16] = f2bf(fmaxf(ac1[r] + bi1, 0.f));
        }
    }

    // A-fragments for GEMM2: this wave's full [16 x 320] from H1 (40 VGPRs)
    s16x8 a2[10];
    #pragma unroll
    for (int s = 0; s < 10; ++s) a2[s] = ldv(H1w + col * 328 + s * 32 + kq * 8);

    f32x4 mac[7];
    #pragma unroll
    for (int u = 0; u < 7; ++u) { f32x4 z = {0.f, 0.f, 0.f, 0.f}; mac[u] = z; }

    // GEMM2 (K=320) fused with GEMM3 in 32-wide chunks of H2
    #pragma unroll 1
    for (int ch = 0; ch < 10; ++ch) {
        const int n0 = ch * 32;
        f32x4 z = {0.f, 0.f, 0.f, 0.f};
        f32x4 ac0 = z, ac1 = z;
        const u16* w0 = W2 + (size_t)(n0 + col) * 320 + kq * 8;
        #pragma unroll
        for (int s = 0; s < 10; ++s) {
            s16x8 b0 = ldv(w0 + s * 32);
            s16x8 b1 = ldv(w0 + 16 * 320 + s * 32);
            ac0 = MFMA(a2[s], b0, ac0);
            ac1 = MFMA(a2[s], b1, ac1);
        }
        const int n = n0 + col;
        const float bi0 = (n < 300)      ? B2[n]      : 0.f;
        const float bi1 = (n + 16 < 300) ? B2[n + 16] : 0.f;
        #pragma unroll
        for (int r = 0; r < 4; ++r) {
            int row = kq * 4 + r;
            SCw[row * 40 + col]      = f2bf(fmaxf(ac0[r] + bi0, 0.f));
            SCw[row * 40 + col + 16] = f2bf(fmaxf(ac1[r] + bi1, 0.f));
        }
        // wave-private SCw: lgkmcnt ordering only, no barrier
        s16x8 a3 = ldv(SCw + col * 40 + kq * 8);
        #pragma unroll
        for (int u = 0; u < 7; ++u) {
            s16x8 b = ldv(W3 + (size_t)(u * 16 + col) * 320 + n0 + kq * 8);
            mac[u] = MFMA(a3, b, mac[u]);
        }
    }

    // scatter-max: per (u,r) instruction lanes cover 16 consecutive channels
    // x 4 edges -> coalesced atomic sectors. Msgs clamped >=0 (see header).
    const int e0 = ebase + kq * 4;
    int dsts[4];
    #pragma unroll
    for (int r = 0; r < 4; ++r) dsts[r] = ei[E_ + e0 + r];
    #pragma unroll
    for (int u = 0; u < 7; ++u) {
        int c3 = u * 16 + col;
        if (c3 < 100) {
            float bi = B3[c3];
            #pragma unroll
            for (int r = 0; r < 4; ++r) {
                float v = fmaxf(mac[u][r] + bi, 0.f);
                atomicMax((int*)(agg + (size_t)dsts[r] * 100 + c3), __float_as_int(v));
            }
        }
    }
}

// ---------------------------------------------------------------------------
// pool: one block per graph (batch sorted -> binary-search bounds).
// pooled[g] = [addp(100) | meanp(100) | maxp(100) | u(2)]
// ---------------------------------------------------------------------------
__global__ __launch_bounds__(256)
void pool(const float* __restrict__ agg1, const int* __restrict__ batch,
          const float* __restrict__ u, float* __restrict__ pooled)
{
    const int g = blockIdx.x;
    int lo = 0, hi = N_;
    while (lo < hi) { int mid = (lo + hi) >> 1; if (batch[mid] < g) lo = mid + 1; else hi = mid; }
    const int start = lo;
    int lo2 = start, hi2 = N_;
    while (lo2 < hi2) { int mid = (lo2 + hi2) >> 1; if (batch[mid] < g + 1) lo2 = mid + 1; else hi2 = mid; }
    const int end = lo2;

    const int c = threadIdx.x & 127, half = threadIdx.x >> 7;
    float sm = 0.f, mx = 0.f;
    if (c < 100)
        for (int n = start + half; n < end; n += 2) {
            float v = agg1[(size_t)n * 100 + c];
            sm += v; mx = fmaxf(mx, v);
        }
    __shared__ float ssum[128], smax[128];
    if (half) { ssum[c] = sm; smax[c] = mx; }
    __syncthreads();
    if (!half && c < 100) {
        sm += ssum[c]; mx = fmaxf(mx, smax[c]);
        int cnt = end - start;
        pooled[g * 302 + c]       = sm;
        pooled[g * 302 + 100 + c] = sm / fmaxf((float)cnt, 1.f);
        pooled[g * 302 + 200 + c] = mx;   // h>=0 so zero-init max == where(cnt>0,.)
    }
    if (threadIdx.x == 0) {
        pooled[g * 302 + 300] = u[g * 2];
        pooled[g * 302 + 301] = u[g * 2 + 1];
    }
}

// ---------------------------------------------------------------------------
// final 302 -> 100 -> 100 -> 2 MLP, one block per graph, fp32
// ---------------------------------------------------------------------------
__global__ __launch_bounds__(128)
void final_mlp(const float* __restrict__ pooled,
               const float* __restrict__ w1, const float* __restrict__ b1,
               const float* __restrict__ w2, const float* __restrict__ b2,
               const float* __restrict__ w3, const float* __restrict__ b3,
               float* __restrict__ out)
{
    const int g = blockIdx.x, t = threadIdx.x;
    __shared__ float P[302], T1[100], T2[100];
    for (int i = t; i < 302; i += 128) P[i] = pooled[g * 302 + i];
    __syncthreads();
    if (t < 100) {
        float a = b1[t];
        for (int i = 0; i < 302; ++i) a = fmaf(P[i], w1[i * 100 + t], a);
        T1[t] = fmaxf(a, 0.f);
    }
    __syncthreads();
    if (t < 100) {
        float a = b2[t];
        for (int i = 0; i < 100; ++i) a = fmaf(T1[i], w2[i * 100 + t], a);
        T2[t] = fmaxf(a, 0.f);
    }
    __syncthreads();
    if (t < 2) {
        float a = b3[t];
        for (int i = 0; i < 100; ++i) a = fmaf(T2[i], w3[i * 2 + t], a);
        out[g * 2 + t] = a;
    }
}

// ---------------------------------------------------------------------------
extern "C" void kernel_launch(void* const* d_in, const int* in_sizes, int n_in,
                              void* d_out, int out_size, void* d_ws, size_t ws_size,
                              hipStream_t stream)
{
    const float* x     = (const float*)d_in[0];
    const int*   ei    = (const int*)d_in[1];
    const int*   batch = (const int*)d_in[2];
    const float* uu    = (const float*)d_in[3];
    const float *l0w1 = (const float*)d_in[4],  *l0b1 = (const float*)d_in[5];
    const float *l0w2 = (const float*)d_in[6],  *l0b2 = (const float*)d_in[7];
    const float *l0w3 = (const float*)d_in[8],  *l0b3 = (const float*)d_in[9];
    const float *l1w1 = (const float*)d_in[10], *l1b1 = (const float*)d_in[11];
    const float *l1w2 = (const float*)d_in[12], *l1b2 = (const float*)d_in[13];
    const float *l1w3 = (const float*)d_in[14], *l1b3 = (const float*)d_in[15];
    const float *lw1  = (const float*)d_in[16], *lb1  = (const float*)d_in[17];
    const float *lw2  = (const float*)d_in[18], *lb2  = (const float*)d_in[19];
    const float *lw3  = (const float*)d_in[20], *lb3  = (const float*)d_in[21];

    char* w = (char*)d_ws;
    float* agg0   = (float*)(w);                    // 20,000,000 B
    float* agg1   = (float*)(w + 20000000);         // 20,000,000 B
    float* pooled = (float*)(w + 40000000);         //     77,312 B
    u16* wt0  = (u16*)(w + 40077312);               //     20,480 B
    u16* wt1  = (u16*)(w + 40097792);               //    143,360 B
    u16* wt2a = (u16*)(w + 40241152);               //    204,800 B
    u16* wt2b = (u16*)(w + 40445952);               //    204,800 B
    u16* wt3a = (u16*)(w + 40650752);               //     71,680 B
    u16* wt3b = (u16*)(w + 40722432);               //     71,680 B  (total ~38.9 MiB)

    ModelGNN_35304631174019_kernel<<<11166, 256, 0, stream>>>(
        l0w1, l0w2, l0w3, l1w1, l1w2, l1w3,
        (float4*)d_ws, wt0, wt1, wt2a, wt2b, wt3a, wt3b);
    edge_mlp<true ><<<6250, 256, 0, stream>>>(x, nullptr, ei, wt0, l0b1, wt2a, l0b2, wt3a, l0b3, agg0);
    edge_mlp<false><<<6250, 256, 0, stream>>>(nullptr, agg0, ei, wt1, l1b1, wt2b, l1b2, wt3b, l1b3, agg1);
    pool<<<G_, 256, 0, stream>>>(agg1, batch, uu, pooled);
    final_mlp<<<G_, 128, 0, stream>>>(pooled, lw1, lb1, lw2, lb2, lw3, lb3, (float*)d_out);
}

// Round 9
// 1445.607 us; speedup vs baseline: 4.9078x; 1.4483x over previous
//
#include <hip/hip_runtime.h>

typedef unsigned short u16;
typedef short s16x8 __attribute__((ext_vector_type(8)));   // 8 bf16 bit-patterns
typedef float f32x4 __attribute__((ext_vector_type(4)));

#define DI __device__ __forceinline__

constexpr int N_ = 50000;
constexpr int E_ = 400000;
constexpr int G_ = 64;

DI u16 f2bf(float f) {
    union { unsigned u; float f; } c; c.f = f;
    unsigned u = c.u;
    u += 0x7fffu + ((u >> 16) & 1u);   // RNE
    return (u16)(u >> 16);
}

DI s16x8 ldv(const u16* p) { return *(const s16x8*)p; }
DI f32x4 MFMA(s16x8 a, s16x8 b, f32x4 c) {
    return __builtin_amdgcn_mfma_f32_16x16x32_bf16(a, b, c, 0, 0, 0);
}

// ---------------------------------------------------------------------------
// Named kernel (symbol required by harness): zero agg0+agg1 (40 MB) and
// repack weights f32 -> bf16 in MFMA-FRAGMENT-ORDER TILES, folding
//   [xi, xj-xi] @ W = xi @ (W_a - W_b) + xj @ W_b.
// Tile layout (all W1/W2): section = 512 elems = 1 KB, holding the B-fragment
// for one (n-half, k-chunk) in exact lane order: elem(col,kq,j) at
// col*32 + kq*8 + j. Section id = n0c*(2*KA) + s*2 + b01 (b01 = n-half).
// -> each wave B-load is 1 KB fully contiguous (8 whole 128B lines), vs
// R8's 16 scattered 64B segments at 448B stride (the L2-request bottleneck).
// W3: section id = ch*7 + u, elem(col,kq,j): n3 = u*16+col, k = ch*32+kq*8+j.
// ---------------------------------------------------------------------------
__global__ __launch_bounds__(256)
void ModelGNN_35304631174019_kernel(
          const float* __restrict__ l0w1, const float* __restrict__ l0w2,
          const float* __restrict__ l0w3, const float* __restrict__ l1w1,
          const float* __restrict__ l1w2, const float* __restrict__ l1w3,
          float4* __restrict__ aggz,
          u16* __restrict__ wt0, u16* __restrict__ wt1,
          u16* __restrict__ wt2a, u16* __restrict__ wt2b,
          u16* __restrict__ wt3a, u16* __restrict__ wt3b)
{
    int i = blockIdx.x * 256 + threadIdx.x;
    if (i < 2500000) { aggz[i] = make_float4(0.f, 0.f, 0.f, 0.f); return; }  // agg0+agg1
    int f = i - 2500000;

    if (f < 10240) {                       // wt0: layer0 W1, KP=32 (KA=1)
        int sec = f >> 9, w = f & 511;
        int col = w >> 5, rem = w & 31;
        int n0c = sec >> 1, b01 = sec & 1;
        int n = n0c * 32 + b01 * 16 + col, k = rem;
        u16 v = 0;
        if (n < 300) {
            if (k < 7) v = f2bf(l0w1[k * 300 + n] - l0w1[(7 + k) * 300 + n]);
            else if (k >= 16 && k < 23) v = f2bf(l0w1[(7 + (k - 16)) * 300 + n]);
        }
        wt0[f] = v; return;
    }
    f -= 10240;
    if (f < 71680) {                       // wt1: layer1 W1, KP=224 (KA=7)
        int sec = f >> 9, w = f & 511;
        int col = w >> 5, rem = w & 31;
        int n0c = sec / 14, r = sec % 14;
        int s = r >> 1, b01 = r & 1;
        int n = n0c * 32 + b01 * 16 + col, k = s * 32 + rem;
        u16 v = 0;
        if (n < 300) {
            if (k < 100) v = f2bf(l1w1[k * 300 + n] - l1w1[(100 + k) * 300 + n]);
            else if (k >= 112 && k < 212) v = f2bf(l1w1[(100 + (k - 112)) * 300 + n]);
        }
        wt1[f] = v; return;
    }
    f -= 71680;
    if (f < 204800) {                      // wt2a / wt2b: 300x300, K=320 (KA=10)
        const float* src = (f < 102400) ? l0w2 : l1w2;
        u16* dst = (f < 102400) ? wt2a : wt2b;
        int f2 = (f < 102400) ? f : f - 102400;
        int sec = f2 >> 9, w = f2 & 511;
        int col = w >> 5, rem = w & 31;
        int n0c = sec / 20, r = sec % 20;
        int s = r >> 1, b01 = r & 1;
        int n = n0c * 32 + b01 * 16 + col, k = s * 32 + rem;
        dst[f2] = (n < 300 && k < 300) ? f2bf(src[k * 300 + n]) : (u16)0;
        return;
    }
    f -= 204800;
    if (f < 71680) {                       // wt3a / wt3b: 300x100 -> [112 n3][320 k]
        const float* src = (f < 35840) ? l0w3 : l1w3;
        u16* dst = (f < 35840) ? wt3a : wt3b;
        int f2 = (f < 35840) ? f : f - 35840;
        int sec = f2 >> 9, w = f2 & 511;
        int col = w >> 5, rem = w & 31;
        int ch = sec / 7, u = sec % 7;
        int n3 = u * 16 + col, k = ch * 32 + rem;
        dst[f2] = (n3 < 100 && k < 300) ? f2bf(src[k * 100 + n3]) : (u16)0;
        return;
    }
}

// ---------------------------------------------------------------------------
// edge_mlp: fused per-edge 3-layer MLP + clamped scatter-max via MFMA.
// One wave = 16 edges; wave-private LDS; no barriers (intra-wave lgkmcnt
// ordering suffices). Weights are in fragment-order tiles (see prep):
// every B-load is a single contiguous 1 KB wave-load.
// Layouts (m89/m120): A: m=lane&15,k=quad*8+j ; B: n=lane&15,k=quad*8+j ;
// C/D: col=lane&15, row=quad*4+reg.
// relu(where(cnt>0,segmax,0)) == int atomicMax of relu'd msgs into 0-init buf.
// ---------------------------------------------------------------------------
template<bool FIRST>
__global__ __launch_bounds__(256)
void edge_mlp(const float* __restrict__ X, const float* __restrict__ H0,
              const int* __restrict__ ei,
              const u16* __restrict__ W1, const float* __restrict__ B1,
              const u16* __restrict__ W2, const float* __restrict__ B2,
              const u16* __restrict__ W3, const float* __restrict__ B3,
              float* __restrict__ agg)
{
    constexpr int KP = FIRST ? 32 : 224;
    constexpr int KA = KP / 32;
    __shared__ __align__(16) u16 H1s[4 * 16 * 328];   // 41,984 B (wave-private slices)
    __shared__ __align__(16) u16 SCR[4 * 16 * 40];    //  5,120 B (wave-private slices)

    const int tid  = threadIdx.x;
    const int wave = tid >> 6, lane = tid & 63;
    const int col  = lane & 15, kq = lane >> 4;
    const int ebase = blockIdx.x * 64 + wave * 16;
    const int fragoff = col * 32 + kq * 8;            // in-section lane offset

    u16* H1w = H1s + wave * (16 * 328);
    u16* SCw = SCR + wave * (16 * 40);

    s16x8 aF[KA];
    if constexpr (FIRST) {
        // gather [xi | xj] into SCw as bf16 IN[16][40] (K padded to 32)
        for (int s = lane; s < 16 * 32; s += 64) {
            int e = s >> 5, k = s & 31;
            u16 v = 0;
            if (k < 7)                  v = f2bf(X[(size_t)ei[E_ + ebase + e] * 7 + k]);
            else if (k >= 16 && k < 23) v = f2bf(X[(size_t)ei[ebase + e] * 7 + (k - 16)]);
            SCw[e * 40 + k] = v;
        }
        #pragma unroll
        for (int s = 0; s < KA; ++s) aF[s] = ldv(SCw + col * 40 + s * 32 + kq * 8);
    } else {
        // build A-fragments directly from global agg0 (h0, f32 -> bf16)
        const int dn = ei[E_ + ebase + col];   // dst node (x_i) of this lane's edge
        const int sn = ei[ebase + col];        // src node (x_j)
        #pragma unroll
        for (int s = 0; s < KA; ++s) {
            int b = s * 4 + kq;                // 8-elem k-group, 0..27; k = 8b+j
            int node = (b < 14) ? dn : sn;
            int c = ((b < 14) ? b : b - 14) * 8;
            s16x8 t = {0, 0, 0, 0, 0, 0, 0, 0};
            if (c < 104) {
                const float* r = H0 + (size_t)node * 100 + c;
                float4 lo = *(const float4*)r;
                t[0] = (short)f2bf(lo.x); t[1] = (short)f2bf(lo.y);
                t[2] = (short)f2bf(lo.z); t[3] = (short)f2bf(lo.w);
                if (c < 96) {
                    float4 hi = *(const float4*)(r + 4);
                    t[4] = (short)f2bf(hi.x); t[5] = (short)f2bf(hi.y);
                    t[6] = (short)f2bf(hi.z); t[7] = (short)f2bf(hi.w);
                }
            }
            aF[s] = t;
        }
    }

    // GEMM1: [16,KP] x Wt1 -> H1[16][320] (relu, bf16)
    #pragma unroll 1
    for (int t2 = 0; t2 < 10; ++t2) {
        const int n0 = t2 * 32;
        f32x4 z = {0.f, 0.f, 0.f, 0.f};
        f32x4 ac0 = z, ac1 = z;
        const u16* w0 = W1 + (size_t)(t2 * 2 * KA) * 512 + fragoff;
        #pragma unroll
        for (int s = 0; s < KA; ++s) {
            s16x8 b0 = ldv(w0 + (2 * s) * 512);       // contiguous 1 KB wave-load
            s16x8 b1 = ldv(w0 + (2 * s + 1) * 512);
            ac0 = MFMA(aF[s], b0, ac0);
            ac1 = MFMA(aF[s], b1, ac1);
        }
        const int n = n0 + col;
        const float bi0 = (n < 300)      ? B1[n]      : 0.f;
        const float bi1 = (n + 16 < 300) ? B1[n + 16] : 0.f;
        #pragma unroll
        for (int r = 0; r < 4; ++r) {
            int row = kq * 4 + r;
            H1w[row * 328 + n]      = f2bf(fmaxf(ac0[r] + bi0, 0.f));
            H1w[row * 328 + n + 16] = f2bf(fmaxf(ac1[r] + bi1, 0.f));
        }
    }

    // A-fragments for GEMM2: this wave's full [16 x 320] from H1 (40 VGPRs)
    s16x8 a2[10];
    #pragma unroll
    for (int s = 0; s < 10; ++s) a2[s] = ldv(H1w + col * 328 + s * 32 + kq * 8);

    f32x4 mac[7];
    #pragma unroll
    for (int u = 0; u < 7; ++u) { f32x4 z = {0.f, 0.f, 0.f, 0.f}; mac[u] = z; }

    // GEMM2 (K=320) fused with GEMM3 in 32-wide chunks of H2
    #pragma unroll 1
    for (int ch = 0; ch < 10; ++ch) {
        const int n0 = ch * 32;
        f32x4 z = {0.f, 0.f, 0.f, 0.f};
        f32x4 ac0 = z, ac1 = z;
        const u16* w0 = W2 + (size_t)(ch * 20) * 512 + fragoff;
        #pragma unroll
        for (int s = 0; s < 10; ++s) {
            s16x8 b0 = ldv(w0 + (2 * s) * 512);       // contiguous 1 KB wave-load
            s16x8 b1 = ldv(w0 + (2 * s + 1) * 512);
            ac0 = MFMA(a2[s], b0, ac0);
            ac1 = MFMA(a2[s], b1, ac1);
        }
        const int n = n0 + col;
        const float bi0 = (n < 300)      ? B2[n]      : 0.f;
        const float bi1 = (n + 16 < 300) ? B2[n + 16] : 0.f;
        #pragma unroll
        for (int r = 0; r < 4; ++r) {
            int row = kq * 4 + r;
            SCw[row * 40 + col]      = f2bf(fmaxf(ac0[r] + bi0, 0.f));
            SCw[row * 40 + col + 16] = f2bf(fmaxf(ac1[r] + bi1, 0.f));
        }
        // wave-private SCw: lgkmcnt ordering only, no barrier
        s16x8 a3 = ldv(SCw + col * 40 + kq * 8);
        #pragma unroll
        for (int u = 0; u < 7; ++u) {
            s16x8 b = ldv(W3 + (size_t)(ch * 7 + u) * 512 + fragoff);  // 1 KB contiguous
            mac[u] = MFMA(a3, b, mac[u]);
        }
    }

    // scatter-max: per (u,r) instruction lanes cover 16 consecutive channels
    // x 4 edges -> coalesced atomic sectors. Msgs clamped >=0 (see header).
    const int e0 = ebase + kq * 4;
    int dsts[4];
    #pragma unroll
    for (int r = 0; r < 4; ++r) dsts[r] = ei[E_ + e0 + r];
    #pragma unroll
    for (int u = 0; u < 7; ++u) {
        int c3 = u * 16 + col;
        if (c3 < 100) {
            float bi = B3[c3];
            #pragma unroll
            for (int r = 0; r < 4; ++r) {
                float v = fmaxf(mac[u][r] + bi, 0.f);
                atomicMax((int*)(agg + (size_t)dsts[r] * 100 + c3), __float_as_int(v));
            }
        }
    }
}

// ---------------------------------------------------------------------------
// pool: one block per graph (batch sorted -> binary-search bounds).
// pooled[g] = [addp(100) | meanp(100) | maxp(100) | u(2)]
// ---------------------------------------------------------------------------
__global__ __launch_bounds__(256)
void pool(const float* __restrict__ agg1, const int* __restrict__ batch,
          const float* __restrict__ u, float* __restrict__ pooled)
{
    const int g = blockIdx.x;
    int lo = 0, hi = N_;
    while (lo < hi) { int mid = (lo + hi) >> 1; if (batch[mid] < g) lo = mid + 1; else hi = mid; }
    const int start = lo;
    int lo2 = start, hi2 = N_;
    while (lo2 < hi2) { int mid = (lo2 + hi2) >> 1; if (batch[mid] < g + 1) lo2 = mid + 1; else hi2 = mid; }
    const int end = lo2;

    const int c = threadIdx.x & 127, half = threadIdx.x >> 7;
    float sm = 0.f, mx = 0.f;
    if (c < 100)
        for (int n = start + half; n < end; n += 2) {
            float v = agg1[(size_t)n * 100 + c];
            sm += v; mx = fmaxf(mx, v);
        }
    __shared__ float ssum[128], smax[128];
    if (half) { ssum[c] = sm; smax[c] = mx; }
    __syncthreads();
    if (!half && c < 100) {
        sm += ssum[c]; mx = fmaxf(mx, smax[c]);
        int cnt = end - start;
        pooled[g * 302 + c]       = sm;
        pooled[g * 302 + 100 + c] = sm / fmaxf((float)cnt, 1.f);
        pooled[g * 302 + 200 + c] = mx;   // h>=0 so zero-init max == where(cnt>0,.)
    }
    if (threadIdx.x == 0) {
        pooled[g * 302 + 300] = u[g * 2];
        pooled[g * 302 + 301] = u[g * 2 + 1];
    }
}

// ---------------------------------------------------------------------------
// final 302 -> 100 -> 100 -> 2 MLP, one block per graph, fp32
// ---------------------------------------------------------------------------
__global__ __launch_bounds__(128)
void final_mlp(const float* __restrict__ pooled,
               const float* __restrict__ w1, const float* __restrict__ b1,
               const float* __restrict__ w2, const float* __restrict__ b2,
               const float* __restrict__ w3, const float* __restrict__ b3,
               float* __restrict__ out)
{
    const int g = blockIdx.x, t = threadIdx.x;
    __shared__ float P[302], T1[100], T2[100];
    for (int i = t; i < 302; i += 128) P[i] = pooled[g * 302 + i];
    __syncthreads();
    if (t < 100) {
        float a = b1[t];
        for (int i = 0; i < 302; ++i) a = fmaf(P[i], w1[i * 100 + t], a);
        T1[t] = fmaxf(a, 0.f);
    }
    __syncthreads();
    if (t < 100) {
        float a = b2[t];
        for (int i = 0; i < 100; ++i) a = fmaf(T1[i], w2[i * 100 + t], a);
        T2[t] = fmaxf(a, 0.f);
    }
    __syncthreads();
    if (t < 2) {
        float a = b3[t];
        for (int i = 0; i < 100; ++i) a = fmaf(T2[i], w3[i * 2 + t], a);
        out[g * 2 + t] = a;
    }
}

// ---------------------------------------------------------------------------
extern "C" void kernel_launch(void* const* d_in, const int* in_sizes, int n_in,
                              void* d_out, int out_size, void* d_ws, size_t ws_size,
                              hipStream_t stream)
{
    const float* x     = (const float*)d_in[0];
    const int*   ei    = (const int*)d_in[1];
    const int*   batch = (const int*)d_in[2];
    const float* uu    = (const float*)d_in[3];
    const float *l0w1 = (const float*)d_in[4],  *l0b1 = (const float*)d_in[5];
    const float *l0w2 = (const float*)d_in[6],  *l0b2 = (const float*)d_in[7];
    const float *l0w3 = (const float*)d_in[8],  *l0b3 = (const float*)d_in[9];
    const float *l1w1 = (const float*)d_in[10], *l1b1 = (const float*)d_in[11];
    const float *l1w2 = (const float*)d_in[12], *l1b2 = (const float*)d_in[13];
    const float *l1w3 = (const float*)d_in[14], *l1b3 = (const float*)d_in[15];
    const float *lw1  = (const float*)d_in[16], *lb1  = (const float*)d_in[17];
    const float *lw2  = (const float*)d_in[18], *lb2  = (const float*)d_in[19];
    const float *lw3  = (const float*)d_in[20], *lb3  = (const float*)d_in[21];

    char* w = (char*)d_ws;
    float* agg0   = (float*)(w);                    // 20,000,000 B
    float* agg1   = (float*)(w + 20000000);         // 20,000,000 B
    float* pooled = (float*)(w + 40000000);         //     77,312 B
    u16* wt0  = (u16*)(w + 40077312);               //     20,480 B
    u16* wt1  = (u16*)(w + 40097792);               //    143,360 B
    u16* wt2a = (u16*)(w + 40241152);               //    204,800 B
    u16* wt2b = (u16*)(w + 40445952);               //    204,800 B
    u16* wt3a = (u16*)(w + 40650752);               //     71,680 B
    u16* wt3b = (u16*)(w + 40722432);               //     71,680 B  (total ~38.9 MiB)

    ModelGNN_35304631174019_kernel<<<11166, 256, 0, stream>>>(
        l0w1, l0w2, l0w3, l1w1, l1w2, l1w3,
        (float4*)d_ws, wt0, wt1, wt2a, wt2b, wt3a, wt3b);
    edge_mlp<true ><<<6250, 256, 0, stream>>>(x, nullptr, ei, wt0, l0b1, wt2a, l0b2, wt3a, l0b3, agg0);
    edge_mlp<false><<<6250, 256, 0, stream>>>(nullptr, agg0, ei, wt1, l1b1, wt2b, l1b2, wt3b, l1b3, agg1);
    pool<<<G_, 256, 0, stream>>>(agg1, batch, uu, pooled);
    final_mlp<<<G_, 128, 0, stream>>>(pooled, lw1, lb1, lw2, lb2, lw3, lb3, (float*)d_out);
}